// Round 1
// baseline (136.227 us; speedup 1.0000x reference)
//
#include <hip/hip_runtime.h>

constexpr int Nn = 64, Tt = 512, Vv = 17, Cc = 3, Oo = 64;
constexpr int TV  = Tt * Vv;      // 8704
constexpr int CTV = Cc * TV;      // 26112
constexpr int NT  = Nn * Tt;      // 32768
constexpr float EPSf = 1e-5f;
constexpr int TCH = 64;

__device__ inline double wave_reduce_add(double v) {
#pragma unroll
  for (int off = 32; off > 0; off >>= 1) v += __shfl_down(v, off, 64);
  return v;
}

// K1: a1[n,t,v], a2[n,t,v] and global s-statistics.
// s[n,t,i,j] = a1[j] + g[i], g = convT_b - a2.
__global__ void __launch_bounds__(256) k_a12(
    const float* __restrict__ x,
    const float* __restrict__ w1, const float* __restrict__ b1,
    const float* __restrict__ w2, const float* __restrict__ b2,
    const float* __restrict__ cw, const float* __restrict__ cb,
    float* __restrict__ a1, float* __restrict__ a2, double* __restrict__ sstats)
{
  int tid = blockIdx.x * blockDim.x + threadIdx.x;
  float u1[3], u2[3];
#pragma unroll
  for (int k = 0; k < 3; ++k) {
    float s1 = 0.f, s2 = 0.f;
#pragma unroll
    for (int c = 0; c < 3; ++c) { s1 += cw[c] * w1[c * 3 + k]; s2 += cw[c] * w2[c * 3 + k]; }
    u1[k] = s1; u2[k] = s2;
  }
  float d1 = 0.f, d2 = 0.f;
#pragma unroll
  for (int c = 0; c < 3; ++c) { d1 += b1[c] * cw[c]; d2 += b2[c] * cw[c]; }
  float b = cb[0];

  float Asum = 0.f, Gsum = 0.f, Q1 = 0.f, Q2 = 0.f;
  if (tid < NT) {
    const float* xp = x + (size_t)tid * (Vv * Cc);
    float* p1 = a1 + (size_t)tid * Vv;
    float* p2 = a2 + (size_t)tid * Vv;
#pragma unroll
    for (int v = 0; v < Vv; ++v) {
      float x0 = xp[v * 3 + 0], x1 = xp[v * 3 + 1], x2 = xp[v * 3 + 2];
      float va1 = fmaf(x0, u1[0], fmaf(x1, u1[1], fmaf(x2, u1[2], d1)));
      float va2 = fmaf(x0, u2[0], fmaf(x1, u2[1], fmaf(x2, u2[2], d2)));
      p1[v] = va1; p2[v] = va2;
      float g = b - va2;
      Asum += va1; Gsum += g;
      Q1 = fmaf(va1, va1, Q1); Q2 = fmaf(g, g, Q2);
    }
  }
  double st[5] = { (double)Asum, (double)Gsum, (double)Q1, (double)Q2,
                   (double)Asum * (double)Gsum };
  __shared__ double red[4];
#pragma unroll
  for (int s = 0; s < 5; ++s) {
    double v = wave_reduce_add(st[s]);
    int wv = threadIdx.x >> 6, ln = threadIdx.x & 63;
    if (ln == 0) red[wv] = v;
    __syncthreads();
    if (threadIdx.x == 0) atomicAdd(&sstats[s], red[0] + red[1] + red[2] + red[3]);
    __syncthreads();
  }
}

// K2: finalize mean/var of s -> affine (scale, shift) for s' = relu(scale*(a1-a2) + shift)
__global__ void k_sparams(const double* __restrict__ sstats,
    const float* __restrict__ cb, const float* __restrict__ cg,
    const float* __restrict__ cbeta, float* __restrict__ sparams)
{
  double S1 = sstats[0], S2 = sstats[1], Q1 = sstats[2], Q2 = sstats[3], X = sstats[4];
  double cnt = (double)Nn * Tt * Vv * Vv;
  double mean = ((double)Vv * (S1 + S2)) / cnt;
  double m2 = ((double)Vv * (Q1 + Q2) + 2.0 * X) / cnt;
  double var = m2 - mean * mean;
  double scale = (double)cg[0] / sqrt(var + (double)EPSf);
  double shift = (double)cbeta[0] + scale * ((double)cb[0] - mean);
  sparams[0] = (float)scale; sparams[1] = (float)shift;
}

// K3: a3 accumulation. block = (t-chunk, n); thread = (i,j).
__global__ void __launch_bounds__(320) k_a3(
    const float* __restrict__ a1, const float* __restrict__ a2,
    const float* __restrict__ sparams, float* __restrict__ a3acc)
{
  __shared__ float l1[(TCH + 1) * Vv];
  __shared__ float l2[(TCH + 1) * Vv];
  int n = blockIdx.y, t0 = blockIdx.x * TCH;
  int tend = t0 + TCH; if (tend > Tt - 1) tend = Tt - 1;
  int nload = tend - t0 + 1;
  int total = nload * Vv;
  const float* b1p = a1 + ((size_t)n * Tt + t0) * Vv;
  const float* b2p = a2 + ((size_t)n * Tt + t0) * Vv;
  for (int idx = threadIdx.x; idx < total; idx += blockDim.x) { l1[idx] = b1p[idx]; l2[idx] = b2p[idx]; }
  __syncthreads();
  int tid = threadIdx.x;
  if (tid < Vv * Vv) {
    int i = tid / Vv, j = tid - i * Vv;
    float scale = sparams[0], shift = sparams[1];
    float prev = fmaxf(fmaf(scale, l1[j] - l2[i], shift), 0.f);
    float acc = 0.f;
    for (int r = 1; r < nload; ++r) {
      float cur = fmaxf(fmaf(scale, l1[r * Vv + j] - l2[r * Vv + i], shift), 0.f);
      acc += fabsf(cur - prev);
      prev = cur;
    }
    atomicAdd(&a3acc[tid], acc);
  }
}

// K4: A = PA + alpha * a3/N
__global__ void k_A(const float* __restrict__ PA, const float* __restrict__ alpha,
                    const float* __restrict__ a3acc, float* __restrict__ Amat)
{
  int i = threadIdx.x;
  if (i < Vv * Vv) Amat[i] = fmaf(alpha[i], a3acc[i] * (1.0f / Nn), PA[i]);
}

// K5: y[n,c,t,:] = x[n,c,t,:] @ A  and first/second moments of y and x over (n,t,v).
__global__ void __launch_bounds__(256) k_y(
    const float* __restrict__ x, const float* __restrict__ Amat,
    float* __restrict__ y, double* __restrict__ ystats)
{
  __shared__ float As[Vv * Vv];
  for (int i = threadIdx.x; i < Vv * Vv; i += blockDim.x) As[i] = Amat[i];
  __syncthreads();
  int tid = blockIdx.x * blockDim.x + threadIdx.x;
  float st[18];
#pragma unroll
  for (int s = 0; s < 18; ++s) st[s] = 0.f;
  if (tid < NT) {
    int n = tid / Tt, t = tid - n * Tt;
    const float* xb = x + (size_t)n * CTV + (size_t)t * Vv;
    float* yb = y + (size_t)n * CTV + (size_t)t * Vv;
    float xv[3][17];
#pragma unroll
    for (int c = 0; c < 3; ++c)
#pragma unroll
      for (int u = 0; u < 17; ++u) xv[c][u] = xb[c * TV + u];
#pragma unroll 1
    for (int v = 0; v < Vv; ++v) {
      float y0 = 0.f, y1 = 0.f, y2 = 0.f;
#pragma unroll
      for (int u = 0; u < 17; ++u) {
        float a = As[u * Vv + v];
        y0 = fmaf(xv[0][u], a, y0);
        y1 = fmaf(xv[1][u], a, y1);
        y2 = fmaf(xv[2][u], a, y2);
      }
      yb[0 * TV + v] = y0; yb[1 * TV + v] = y1; yb[2 * TV + v] = y2;
      float x0 = xv[0][v], x1 = xv[1][v], x2 = xv[2][v];
      st[0] += y0; st[1] += y1; st[2] += y2;
      st[3] = fmaf(y0, y0, st[3]); st[4] = fmaf(y0, y1, st[4]); st[5] = fmaf(y0, y2, st[5]);
      st[6] = fmaf(y1, y1, st[6]); st[7] = fmaf(y1, y2, st[7]); st[8] = fmaf(y2, y2, st[8]);
      st[9] += x0; st[10] += x1; st[11] += x2;
      st[12] = fmaf(x0, x0, st[12]); st[13] = fmaf(x0, x1, st[13]); st[14] = fmaf(x0, x2, st[14]);
      st[15] = fmaf(x1, x1, st[15]); st[16] = fmaf(x1, x2, st[16]); st[17] = fmaf(x2, x2, st[17]);
    }
  }
  __shared__ double red[4];
  for (int s = 0; s < 18; ++s) {
    double v = wave_reduce_add((double)st[s]);
    int wv = threadIdx.x >> 6, ln = threadIdx.x & 63;
    if (ln == 0) red[wv] = v;
    __syncthreads();
    if (threadIdx.x == 0) atomicAdd(&ystats[s], red[0] + red[1] + red[2] + red[3]);
    __syncthreads();
  }
}

// K6: per-o fused coefficients (BN-of-z and BN-of-p folded into z+p+relu).
__global__ void k_coef(const double* __restrict__ ystats,
    const float* __restrict__ w2d, const float* __restrict__ b2d,
    const float* __restrict__ bng, const float* __restrict__ bnb,
    const float* __restrict__ pw, const float* __restrict__ pb,
    const float* __restrict__ pg, const float* __restrict__ pbeta,
    float* __restrict__ coef)
{
  int o = threadIdx.x;
  if (o >= Oo) return;
  const double cnt = (double)Nn * Tt * Vv;
  double my[3], Eyy[6], mx[3], Exx[6];
#pragma unroll
  for (int i = 0; i < 3; ++i) my[i] = ystats[i] / cnt;
#pragma unroll
  for (int i = 0; i < 6; ++i) Eyy[i] = ystats[3 + i] / cnt;
#pragma unroll
  for (int i = 0; i < 3; ++i) mx[i] = ystats[9 + i] / cnt;
#pragma unroll
  for (int i = 0; i < 6; ++i) Exx[i] = ystats[12 + i] / cnt;

  double w0 = w2d[o * 3], w1 = w2d[o * 3 + 1], w2 = w2d[o * 3 + 2], bz = b2d[o];
  double wm = w0 * my[0] + w1 * my[1] + w2 * my[2];
  double mz = wm + bz;
  double Ez2 = w0 * w0 * Eyy[0] + 2 * w0 * w1 * Eyy[1] + 2 * w0 * w2 * Eyy[2]
             + w1 * w1 * Eyy[3] + 2 * w1 * w2 * Eyy[4] + w2 * w2 * Eyy[5]
             + 2 * bz * wm + bz * bz;
  double varz = Ez2 - mz * mz;
  double sz = (double)bng[o] / sqrt(varz + (double)EPSf);

  double q0 = pw[o * 3], q1 = pw[o * 3 + 1], q2 = pw[o * 3 + 2], bp = pb[o];
  double qm = q0 * mx[0] + q1 * mx[1] + q2 * mx[2];
  double mp = qm + bp;
  double Ep2 = q0 * q0 * Exx[0] + 2 * q0 * q1 * Exx[1] + 2 * q0 * q2 * Exx[2]
             + q1 * q1 * Exx[3] + 2 * q1 * q2 * Exx[4] + q2 * q2 * Exx[5]
             + 2 * bp * qm + bp * bp;
  double varp = Ep2 - mp * mp;
  double sp = (double)pg[o] / sqrt(varp + (double)EPSf);

  coef[o * 8 + 0] = (float)(sz * w0); coef[o * 8 + 1] = (float)(sz * w1); coef[o * 8 + 2] = (float)(sz * w2);
  coef[o * 8 + 3] = (float)(sp * q0); coef[o * 8 + 4] = (float)(sp * q1); coef[o * 8 + 5] = (float)(sp * q2);
  coef[o * 8 + 6] = (float)(sz * (bz - mz) + (double)bnb[o] + sp * (bp - mp) + (double)pbeta[o]);
  coef[o * 8 + 7] = 0.f;
}

// K7: out[n,o,tv] = relu(sum_c wy*y + sum_c wx*x + be). float4 over tv.
__global__ void __launch_bounds__(128) k_out(
    const float* __restrict__ y, const float* __restrict__ x,
    const float* __restrict__ coef, float* __restrict__ out)
{
  int n = blockIdx.y;
  int tv = blockIdx.x * 512 + threadIdx.x * 4;   // 17 tiles * 512 = 8704 exact
  const float* yb = y + (size_t)n * CTV + tv;
  const float* xb = x + (size_t)n * CTV + tv;
  float4 yq0 = *(const float4*)(yb);
  float4 yq1 = *(const float4*)(yb + TV);
  float4 yq2 = *(const float4*)(yb + 2 * TV);
  float4 xq0 = *(const float4*)(xb);
  float4 xq1 = *(const float4*)(xb + TV);
  float4 xq2 = *(const float4*)(xb + 2 * TV);
  float* ob = out + (size_t)n * (Oo * TV) + tv;
#pragma unroll 4
  for (int o = 0; o < Oo; ++o) {
    float wy0 = coef[o * 8 + 0], wy1 = coef[o * 8 + 1], wy2 = coef[o * 8 + 2];
    float wx0 = coef[o * 8 + 3], wx1 = coef[o * 8 + 4], wx2 = coef[o * 8 + 5];
    float be  = coef[o * 8 + 6];
    float4 r;
    r.x = fmaxf(fmaf(wy0, yq0.x, fmaf(wy1, yq1.x, fmaf(wy2, yq2.x, fmaf(wx0, xq0.x, fmaf(wx1, xq1.x, fmaf(wx2, xq2.x, be)))))), 0.f);
    r.y = fmaxf(fmaf(wy0, yq0.y, fmaf(wy1, yq1.y, fmaf(wy2, yq2.y, fmaf(wx0, xq0.y, fmaf(wx1, xq1.y, fmaf(wx2, xq2.y, be)))))), 0.f);
    r.z = fmaxf(fmaf(wy0, yq0.z, fmaf(wy1, yq1.z, fmaf(wy2, yq2.z, fmaf(wx0, xq0.z, fmaf(wx1, xq1.z, fmaf(wx2, xq2.z, be)))))), 0.f);
    r.w = fmaxf(fmaf(wy0, yq0.w, fmaf(wy1, yq1.w, fmaf(wy2, yq2.w, fmaf(wx0, xq0.w, fmaf(wx1, xq1.w, fmaf(wx2, xq2.w, be)))))), 0.f);
    *(float4*)(ob + (size_t)o * TV) = r;
  }
}

extern "C" void kernel_launch(void* const* d_in, const int* in_sizes, int n_in,
                              void* d_out, int out_size, void* d_ws, size_t ws_size,
                              hipStream_t stream)
{
  (void)in_sizes; (void)n_in; (void)out_size; (void)ws_size;
  const float* x     = (const float*)d_in[0];
  const float* w1    = (const float*)d_in[1];
  const float* b1    = (const float*)d_in[2];
  const float* w2    = (const float*)d_in[3];
  const float* b2    = (const float*)d_in[4];
  const float* cw    = (const float*)d_in[5];
  const float* cb    = (const float*)d_in[6];
  const float* cg    = (const float*)d_in[7];
  const float* cbeta = (const float*)d_in[8];
  const float* PA    = (const float*)d_in[9];
  const float* alpha = (const float*)d_in[10];
  const float* c2w   = (const float*)d_in[11];
  const float* c2b   = (const float*)d_in[12];
  const float* bng   = (const float*)d_in[13];
  const float* bnb   = (const float*)d_in[14];
  const float* pw    = (const float*)d_in[15];
  const float* pb    = (const float*)d_in[16];
  const float* pg    = (const float*)d_in[17];
  const float* pbeta = (const float*)d_in[18];
  float* out = (float*)d_out;

  char* ws = (char*)d_ws;
  double* sstats = (double*)(ws + 0);        // 5 doubles
  double* ystats = (double*)(ws + 64);       // 18 doubles
  float* a3acc   = (float*)(ws + 256);       // 289 floats
  float* sparams = (float*)(ws + 1536);      // 2 floats
  float* Amat    = (float*)(ws + 1600);      // 289 floats
  float* coef    = (float*)(ws + 4096);      // 512 floats
  float* a1      = (float*)(ws + 8192);
  float* a2      = (float*)(ws + 8192 + 2228224);
  float* yy      = (float*)(ws + 8192 + 2 * 2228224);

  hipMemsetAsync(d_ws, 0, 1536, stream);
  hipLaunchKernelGGL(k_a12, dim3(NT / 256), dim3(256), 0, stream,
                     x, w1, b1, w2, b2, cw, cb, a1, a2, sstats);
  hipLaunchKernelGGL(k_sparams, dim3(1), dim3(1), 0, stream, sstats, cb, cg, cbeta, sparams);
  hipLaunchKernelGGL(k_a3, dim3(Tt / TCH, Nn), dim3(320), 0, stream, a1, a2, sparams, a3acc);
  hipLaunchKernelGGL(k_A, dim3(1), dim3(320), 0, stream, PA, alpha, a3acc, Amat);
  hipLaunchKernelGGL(k_y, dim3(NT / 256), dim3(256), 0, stream, x, Amat, yy, ystats);
  hipLaunchKernelGGL(k_coef, dim3(1), dim3(64), 0, stream,
                     ystats, c2w, c2b, bng, bnb, pw, pb, pg, pbeta, coef);
  hipLaunchKernelGGL(k_out, dim3(17, Nn), dim3(128), 0, stream, yy, x, coef, out);
}

// Round 2
// 110.503 us; speedup vs baseline: 1.2328x; 1.2328x over previous
//
#include <hip/hip_runtime.h>

constexpr int Nn = 64, Tt = 512, Vv = 17, Cc = 3, Oo = 64;
constexpr int TV  = Tt * Vv;      // 8704
constexpr int CTV = Cc * TV;      // 26112
constexpr int NT  = Nn * Tt;      // 32768
constexpr float EPSf = 1e-5f;
constexpr int TCH = 256;          // t-chunk for k_a3
constexpr int NBLK_STATS = 128;   // k_stats / k_y blocks

__device__ inline double wave_reduce_add(double v) {
#pragma unroll
  for (int off = 32; off > 0; off >>= 1) v += __shfl_down(v, off, 64);
  return v;
}

// ---------------------------------------------------------------------------
// K1: global s-statistics only (no a1/a2 materialization).
// s[n,t,i,j] = a1[n,t,j] + g[n,t,i], g = convT_b - a2.
// Per-block partials -> spart[block][5], no atomics.
__global__ void __launch_bounds__(256) k_stats(
    const float* __restrict__ x,
    const float* __restrict__ w1, const float* __restrict__ b1,
    const float* __restrict__ w2, const float* __restrict__ b2,
    const float* __restrict__ cw, const float* __restrict__ cb,
    double* __restrict__ spart)
{
  int tid = blockIdx.x * 256 + threadIdx.x;   // grid exact: 128*256 = NT
  float u1[3], u2[3];
#pragma unroll
  for (int k = 0; k < 3; ++k) {
    float s1 = 0.f, s2 = 0.f;
#pragma unroll
    for (int c = 0; c < 3; ++c) { s1 += cw[c] * w1[c * 3 + k]; s2 += cw[c] * w2[c * 3 + k]; }
    u1[k] = s1; u2[k] = s2;
  }
  float d1 = 0.f, d2 = 0.f;
#pragma unroll
  for (int c = 0; c < 3; ++c) { d1 += b1[c] * cw[c]; d2 += b2[c] * cw[c]; }
  float b = cb[0];

  float Asum = 0.f, Gsum = 0.f, Q1 = 0.f, Q2 = 0.f;
  {
    const float* xp = x + (size_t)tid * (Vv * Cc);
#pragma unroll
    for (int v = 0; v < Vv; ++v) {
      float x0 = xp[v * 3 + 0], x1 = xp[v * 3 + 1], x2 = xp[v * 3 + 2];
      float va1 = fmaf(x0, u1[0], fmaf(x1, u1[1], fmaf(x2, u1[2], d1)));
      float va2 = fmaf(x0, u2[0], fmaf(x1, u2[1], fmaf(x2, u2[2], d2)));
      float g = b - va2;
      Asum += va1; Gsum += g;
      Q1 = fmaf(va1, va1, Q1); Q2 = fmaf(g, g, Q2);
    }
  }
  double st[5] = { (double)Asum, (double)Gsum, (double)Q1, (double)Q2,
                   (double)Asum * (double)Gsum };
  __shared__ double red[4][5];
  int wv = threadIdx.x >> 6;
#pragma unroll
  for (int s = 0; s < 5; ++s) {
    double v = wave_reduce_add(st[s]);
    if ((threadIdx.x & 63) == 0) red[wv][s] = v;
  }
  __syncthreads();
  if (threadIdx.x < 5) {
    int s = threadIdx.x;
    spart[(size_t)blockIdx.x * 5 + s] = red[0][s] + red[1][s] + red[2][s] + red[3][s];
  }
}

// ---------------------------------------------------------------------------
// K2: a3 partials. Each block = (t-chunk, n). Recomputes a1/a2 from x into LDS,
// reduces the s-stat partials itself for (scale, shift).
__global__ void __launch_bounds__(320) k_a3(
    const float* __restrict__ x, const double* __restrict__ spart,
    const float* __restrict__ w1, const float* __restrict__ b1,
    const float* __restrict__ w2, const float* __restrict__ b2,
    const float* __restrict__ cw, const float* __restrict__ cb,
    const float* __restrict__ cg, const float* __restrict__ cbeta,
    float* __restrict__ a3part)
{
  __shared__ float l1[(TCH + 1) * Vv];
  __shared__ float l2[(TCH + 1) * Vv];
  __shared__ double red[5][5];
  __shared__ float spLDS[2];
  int t = threadIdx.x;

  // reduce s-stats -> scale/shift (threads 0..127 hold partial rows)
  double v[5];
#pragma unroll
  for (int s = 0; s < 5; ++s) v[s] = (t < NBLK_STATS) ? spart[(size_t)t * 5 + s] : 0.0;
  int wv = t >> 6;
#pragma unroll
  for (int s = 0; s < 5; ++s) {
    double r = wave_reduce_add(v[s]);
    if ((t & 63) == 0) red[wv][s] = r;
  }
  __syncthreads();
  if (t == 0) {
    double S[5];
#pragma unroll
    for (int s = 0; s < 5; ++s) S[s] = red[0][s] + red[1][s] + red[2][s] + red[3][s] + red[4][s];
    double cnt = (double)Nn * Tt * Vv * Vv;
    double mean = ((double)Vv * (S[0] + S[1])) / cnt;
    double m2   = ((double)Vv * (S[2] + S[3]) + 2.0 * S[4]) / cnt;
    double var  = m2 - mean * mean;
    double scale = (double)cg[0] / sqrt(var + (double)EPSf);
    double shift = (double)cbeta[0] + scale * ((double)cb[0] - mean);
    spLDS[0] = (float)scale; spLDS[1] = (float)shift;
  }

  // u1,u2,d1,d2 (redundant per thread; ~25 scalar loads)
  float u1[3], u2[3];
#pragma unroll
  for (int k = 0; k < 3; ++k) {
    float s1 = 0.f, s2 = 0.f;
#pragma unroll
    for (int c = 0; c < 3; ++c) { s1 += cw[c] * w1[c * 3 + k]; s2 += cw[c] * w2[c * 3 + k]; }
    u1[k] = s1; u2[k] = s2;
  }
  float d1 = 0.f, d2 = 0.f;
#pragma unroll
  for (int c = 0; c < 3; ++c) { d1 += b1[c] * cw[c]; d2 += b2[c] * cw[c]; }
  float b = cb[0];

  int n = blockIdx.y, t0 = blockIdx.x * TCH;
  int tend = t0 + TCH; if (tend > Tt - 1) tend = Tt - 1;
  int nload = tend - t0 + 1;
  int total = nload * Vv;
  for (int idx = t; idx < total; idx += 320) {
    int r = idx / Vv, vv = idx - r * Vv;
    const float* xp = x + ((size_t)(n * Tt + t0 + r) * Vv + vv) * 3;
    float x0 = xp[0], x1 = xp[1], x2 = xp[2];
    float va1 = fmaf(x0, u1[0], fmaf(x1, u1[1], fmaf(x2, u1[2], d1)));
    float va2 = fmaf(x0, u2[0], fmaf(x1, u2[1], fmaf(x2, u2[2], d2)));
    l1[idx] = va1; l2[idx] = b - va2;   // s = scale*(a1[j] + g[i]) + shift', fold below
  }
  __syncthreads();
  if (t < Vv * Vv) {
    int i = t / Vv, j = t - i * Vv;
    float scale = spLDS[0], shift = spLDS[1];
    // s' = scale*(l1[j] + l2g[i] - cb) + shift ... careful: l2 holds g = b - a2,
    // and s = a1 + g - ... wait: s = a1[j] - a2[i] + b = l1[j] + l2[i].
    float prev = fmaxf(fmaf(scale, l1[j] + l2[i], shift - scale * b), 0.f);
    // NOTE: shift already includes scale*(b - mean); but l1[j]+l2[i] includes +b.
    // reference: s_raw = a1[j] - a2[i] + b; normalized = scale*(s_raw - mean) + beta
    //          = scale*s_raw + (beta - scale*mean) = scale*(l1[j]+l2[i]) + (shift - scale*b)
    // since shift = beta + scale*(b - mean)  => shift - scale*b = beta - scale*mean. OK.
    float c0 = shift - scale * b;
    float acc = 0.f;
    for (int r = 1; r < nload; ++r) {
      float cur = fmaxf(fmaf(scale, l1[r * Vv + j] + l2[r * Vv + i], c0), 0.f);
      acc += fabsf(cur - prev);
      prev = cur;
    }
    a3part[((size_t)blockIdx.x * Nn + blockIdx.y) * (Vv * Vv) + t] = acc;
  }
}

// ---------------------------------------------------------------------------
// K3: A = PA + alpha * (sum of a3 partials)/N
__global__ void __launch_bounds__(320) k_A(
    const float* __restrict__ PA, const float* __restrict__ alpha,
    const float* __restrict__ a3part, float* __restrict__ Amat)
{
  int j = threadIdx.x;
  if (j < Vv * Vv) {
    float acc = 0.f;
#pragma unroll 4
    for (int bk = 0; bk < 128; ++bk) acc += a3part[(size_t)bk * (Vv * Vv) + j];
    Amat[j] = fmaf(alpha[j], acc * (1.0f / Nn), PA[j]);
  }
}

// ---------------------------------------------------------------------------
// K4: y[n,c,t,:] = x[n,c,t,:] @ A  and moment partials of y and x over (n,t,v).
__global__ void __launch_bounds__(256) k_y(
    const float* __restrict__ x, const float* __restrict__ Amat,
    float* __restrict__ y, double* __restrict__ ypart)
{
  __shared__ float As[Vv * Vv];
  for (int i = threadIdx.x; i < Vv * Vv; i += 256) As[i] = Amat[i];
  __syncthreads();
  int tid = blockIdx.x * 256 + threadIdx.x;   // grid exact
  float st[18];
#pragma unroll
  for (int s = 0; s < 18; ++s) st[s] = 0.f;
  {
    int n = tid / Tt, t = tid - n * Tt;
    const float* xb = x + (size_t)n * CTV + (size_t)t * Vv;
    float* yb = y + (size_t)n * CTV + (size_t)t * Vv;
    float xv[3][17];
#pragma unroll
    for (int c = 0; c < 3; ++c)
#pragma unroll
      for (int u = 0; u < 17; ++u) xv[c][u] = xb[c * TV + u];
#pragma unroll 1
    for (int v = 0; v < Vv; ++v) {
      float y0 = 0.f, y1 = 0.f, y2 = 0.f;
#pragma unroll
      for (int u = 0; u < 17; ++u) {
        float a = As[u * Vv + v];
        y0 = fmaf(xv[0][u], a, y0);
        y1 = fmaf(xv[1][u], a, y1);
        y2 = fmaf(xv[2][u], a, y2);
      }
      yb[0 * TV + v] = y0; yb[1 * TV + v] = y1; yb[2 * TV + v] = y2;
      float x0 = xv[0][v], x1 = xv[1][v], x2 = xv[2][v];
      st[0] += y0; st[1] += y1; st[2] += y2;
      st[3] = fmaf(y0, y0, st[3]); st[4] = fmaf(y0, y1, st[4]); st[5] = fmaf(y0, y2, st[5]);
      st[6] = fmaf(y1, y1, st[6]); st[7] = fmaf(y1, y2, st[7]); st[8] = fmaf(y2, y2, st[8]);
      st[9] += x0; st[10] += x1; st[11] += x2;
      st[12] = fmaf(x0, x0, st[12]); st[13] = fmaf(x0, x1, st[13]); st[14] = fmaf(x0, x2, st[14]);
      st[15] = fmaf(x1, x1, st[15]); st[16] = fmaf(x1, x2, st[16]); st[17] = fmaf(x2, x2, st[17]);
    }
  }
  __shared__ double red[4][18];
  int wv = threadIdx.x >> 6;
#pragma unroll
  for (int s = 0; s < 18; ++s) {
    double v = wave_reduce_add((double)st[s]);
    if ((threadIdx.x & 63) == 0) red[wv][s] = v;
  }
  __syncthreads();
  if (threadIdx.x < 18) {
    int s = threadIdx.x;
    ypart[(size_t)blockIdx.x * 18 + s] = red[0][s] + red[1][s] + red[2][s] + red[3][s];
  }
}

// ---------------------------------------------------------------------------
// K5: reduce moment partials, compute per-o fused coefficients.
__global__ void __launch_bounds__(64) k_coef(
    const double* __restrict__ ypart,
    const float* __restrict__ w2d, const float* __restrict__ b2d,
    const float* __restrict__ bng, const float* __restrict__ bnb,
    const float* __restrict__ pw, const float* __restrict__ pb,
    const float* __restrict__ pg, const float* __restrict__ pbeta,
    float* __restrict__ coef)
{
  __shared__ double sred[18];
  int t = threadIdx.x;   // 64 threads = 1 wave
#pragma unroll
  for (int s = 0; s < 18; ++s) {
    double v = ypart[(size_t)t * 18 + s] + ypart[(size_t)(t + 64) * 18 + s];
    v = wave_reduce_add(v);
    if (t == 0) sred[s] = v;
  }
  __syncthreads();

  int o = t;
  const double cnt = (double)Nn * Tt * Vv;
  double my[3], Eyy[6], mx[3], Exx[6];
#pragma unroll
  for (int i = 0; i < 3; ++i) my[i] = sred[i] / cnt;
#pragma unroll
  for (int i = 0; i < 6; ++i) Eyy[i] = sred[3 + i] / cnt;
#pragma unroll
  for (int i = 0; i < 3; ++i) mx[i] = sred[9 + i] / cnt;
#pragma unroll
  for (int i = 0; i < 6; ++i) Exx[i] = sred[12 + i] / cnt;

  double w0 = w2d[o * 3], w1 = w2d[o * 3 + 1], w2 = w2d[o * 3 + 2], bz = b2d[o];
  double wm = w0 * my[0] + w1 * my[1] + w2 * my[2];
  double mz = wm + bz;
  double Ez2 = w0 * w0 * Eyy[0] + 2 * w0 * w1 * Eyy[1] + 2 * w0 * w2 * Eyy[2]
             + w1 * w1 * Eyy[3] + 2 * w1 * w2 * Eyy[4] + w2 * w2 * Eyy[5]
             + 2 * bz * wm + bz * bz;
  double varz = Ez2 - mz * mz;
  double sz = (double)bng[o] / sqrt(varz + (double)EPSf);

  double q0 = pw[o * 3], q1 = pw[o * 3 + 1], q2 = pw[o * 3 + 2], bp = pb[o];
  double qm = q0 * mx[0] + q1 * mx[1] + q2 * mx[2];
  double mp = qm + bp;
  double Ep2 = q0 * q0 * Exx[0] + 2 * q0 * q1 * Exx[1] + 2 * q0 * q2 * Exx[2]
             + q1 * q1 * Exx[3] + 2 * q1 * q2 * Exx[4] + q2 * q2 * Exx[5]
             + 2 * bp * qm + bp * bp;
  double varp = Ep2 - mp * mp;
  double sp = (double)pg[o] / sqrt(varp + (double)EPSf);

  coef[o * 8 + 0] = (float)(sz * w0); coef[o * 8 + 1] = (float)(sz * w1); coef[o * 8 + 2] = (float)(sz * w2);
  coef[o * 8 + 3] = (float)(sp * q0); coef[o * 8 + 4] = (float)(sp * q1); coef[o * 8 + 5] = (float)(sp * q2);
  coef[o * 8 + 6] = (float)(sz * (bz - mz) + (double)bnb[o] + sp * (bp - mp) + (double)pbeta[o]);
  coef[o * 8 + 7] = 0.f;
}

// ---------------------------------------------------------------------------
// K6: out[n,o,tv] = relu(sum_c wy*y + sum_c wx*x + be). float4 over tv.
__global__ void __launch_bounds__(128) k_out(
    const float* __restrict__ y, const float* __restrict__ x,
    const float* __restrict__ coef, float* __restrict__ out)
{
  int n = blockIdx.y;
  int tv = blockIdx.x * 512 + threadIdx.x * 4;   // 17 tiles * 512 = 8704 exact
  const float* yb = y + (size_t)n * CTV + tv;
  const float* xb = x + (size_t)n * CTV + tv;
  float4 yq0 = *(const float4*)(yb);
  float4 yq1 = *(const float4*)(yb + TV);
  float4 yq2 = *(const float4*)(yb + 2 * TV);
  float4 xq0 = *(const float4*)(xb);
  float4 xq1 = *(const float4*)(xb + TV);
  float4 xq2 = *(const float4*)(xb + 2 * TV);
  float* ob = out + (size_t)n * (Oo * TV) + tv;
#pragma unroll 4
  for (int o = 0; o < Oo; ++o) {
    float wy0 = coef[o * 8 + 0], wy1 = coef[o * 8 + 1], wy2 = coef[o * 8 + 2];
    float wx0 = coef[o * 8 + 3], wx1 = coef[o * 8 + 4], wx2 = coef[o * 8 + 5];
    float be  = coef[o * 8 + 6];
    float4 r;
    r.x = fmaxf(fmaf(wy0, yq0.x, fmaf(wy1, yq1.x, fmaf(wy2, yq2.x, fmaf(wx0, xq0.x, fmaf(wx1, xq1.x, fmaf(wx2, xq2.x, be)))))), 0.f);
    r.y = fmaxf(fmaf(wy0, yq0.y, fmaf(wy1, yq1.y, fmaf(wy2, yq2.y, fmaf(wx0, xq0.y, fmaf(wx1, xq1.y, fmaf(wx2, xq2.y, be)))))), 0.f);
    r.z = fmaxf(fmaf(wy0, yq0.z, fmaf(wy1, yq1.z, fmaf(wy2, yq2.z, fmaf(wx0, xq0.z, fmaf(wx1, xq1.z, fmaf(wx2, xq2.z, be)))))), 0.f);
    r.w = fmaxf(fmaf(wy0, yq0.w, fmaf(wy1, yq1.w, fmaf(wy2, yq2.w, fmaf(wx0, xq0.w, fmaf(wx1, xq1.w, fmaf(wx2, xq2.w, be)))))), 0.f);
    *(float4*)(ob + (size_t)o * TV) = r;
  }
}

extern "C" void kernel_launch(void* const* d_in, const int* in_sizes, int n_in,
                              void* d_out, int out_size, void* d_ws, size_t ws_size,
                              hipStream_t stream)
{
  (void)in_sizes; (void)n_in; (void)out_size; (void)ws_size;
  const float* x     = (const float*)d_in[0];
  const float* w1    = (const float*)d_in[1];
  const float* b1    = (const float*)d_in[2];
  const float* w2    = (const float*)d_in[3];
  const float* b2    = (const float*)d_in[4];
  const float* cw    = (const float*)d_in[5];
  const float* cb    = (const float*)d_in[6];
  const float* cg    = (const float*)d_in[7];
  const float* cbeta = (const float*)d_in[8];
  const float* PA    = (const float*)d_in[9];
  const float* alpha = (const float*)d_in[10];
  const float* c2w   = (const float*)d_in[11];
  const float* c2b   = (const float*)d_in[12];
  const float* bng   = (const float*)d_in[13];
  const float* bnb   = (const float*)d_in[14];
  const float* pw    = (const float*)d_in[15];
  const float* pb    = (const float*)d_in[16];
  const float* pg    = (const float*)d_in[17];
  const float* pbeta = (const float*)d_in[18];
  float* out = (float*)d_out;

  char* ws = (char*)d_ws;
  double* spart  = (double*)(ws + 0);          // 128*5 doubles   = 5120 B
  double* ypart  = (double*)(ws + 5120);       // 128*18 doubles  = 18432 B, ends 23552
  float*  Amat   = (float*)(ws + 23552);       // 289 floats
  float*  coef   = (float*)(ws + 24832);       // 512 floats
  float*  a3part = (float*)(ws + 27136);       // 128*289 floats  = 147968 B, ends 175104
  float*  yy     = (float*)(ws + 176128);      // NT*17 floats    = 2228224 B

  hipLaunchKernelGGL(k_stats, dim3(NBLK_STATS), dim3(256), 0, stream,
                     x, w1, b1, w2, b2, cw, cb, spart);
  hipLaunchKernelGGL(k_a3, dim3(Tt / TCH, Nn), dim3(320), 0, stream,
                     x, spart, w1, b1, w2, b2, cw, cb, cg, cbeta, a3part);
  hipLaunchKernelGGL(k_A, dim3(1), dim3(320), 0, stream, PA, alpha, a3part, Amat);
  hipLaunchKernelGGL(k_y, dim3(NBLK_STATS), dim3(256), 0, stream, x, Amat, yy, ypart);
  hipLaunchKernelGGL(k_coef, dim3(1), dim3(64), 0, stream,
                     ypart, c2w, c2b, bng, bnb, pw, pb, pg, pbeta, coef);
  hipLaunchKernelGGL(k_out, dim3(17, Nn), dim3(128), 0, stream, yy, x, coef, out);
}